// Round 1
// baseline (2826.104 us; speedup 1.0000x reference)
//
#include <hip/hip_runtime.h>
#include <stdint.h>

typedef __attribute__((ext_vector_type(8))) short bf16x8;
typedef __attribute__((ext_vector_type(4))) float f32x4;

__device__ __forceinline__ ushort f2bf(float f) {
  union { float f; uint32_t u; } v; v.f = f;
  return (ushort)((v.u + 0x7FFFu + ((v.u >> 16) & 1u)) >> 16);
}

__device__ __forceinline__ void load_lds16(const void* g, void* l) {
  __builtin_amdgcn_global_load_lds(
      (const __attribute__((address_space(1))) void*)g,
      (__attribute__((address_space(3))) void*)l, 16, 0, 0);
}

// ---- convert x (f32) -> bf16 ----
__global__ void cvt_bf16_kernel(const float4* __restrict__ x, ushort4* __restrict__ o, int n4) {
  int i = blockIdx.x * blockDim.x + threadIdx.x;
  int stride = gridDim.x * blockDim.x;
  for (; i < n4; i += stride) {
    float4 v = x[i];
    o[i] = make_ushort4(f2bf(v.x), f2bf(v.y), f2bf(v.z), f2bf(v.w));
  }
}

// ---- materialize W^T chunk: wt[n*K + k] = bf16(t[(k*Aa + n*Bb + Cp) & mask]) ----
__global__ void mat_wt_kernel(const float* __restrict__ t, ushort* __restrict__ wt,
                              int Klog2, int Kmask, int Aa, int Bb, int Cp,
                              unsigned mask, int total4) {
  int i = blockIdx.x * blockDim.x + threadIdx.x;
  int stride = gridDim.x * blockDim.x;
  for (; i < total4; i += stride) {
    int e = i << 2;
    int n = e >> Klog2;
    int k = e & Kmask;
    int base = k * Aa + n * Bb + Cp;  // < 2^31 by construction
    ushort4 v;
    v.x = f2bf(t[(unsigned)(base) & mask]);
    v.y = f2bf(t[(unsigned)(base + Aa) & mask]);
    v.z = f2bf(t[(unsigned)(base + 2 * Aa) & mask]);
    v.w = f2bf(t[(unsigned)(base + 3 * Aa) & mask]);
    *(ushort4*)(wt + e) = v;
  }
}

// ---- bf16 GEMM: C[M x N-chunk] = A[M x K] @ Bt[N-chunk x K]^T ----
// 128x128 tile, BK=64, 4 waves (2x2), 16x16x32 MFMA, global_load_lds staging.
template <bool RELU_BF16, bool F32OUT>
__global__ __launch_bounds__(256) void gemm_bt(
    const ushort* __restrict__ Ag, const ushort* __restrict__ Bg,
    float* __restrict__ Cf, ushort* __restrict__ Ch,
    int K, int ldc, int colbase) {
  __shared__ ushort lA[128 * 64];
  __shared__ ushort lB[128 * 64];
  const int tid = threadIdx.x;
  const int w = tid >> 6, lane = tid & 63;
  const int mt = blockIdx.x & 15, nt = blockIdx.x >> 4;
  const int m0 = mt * 128, n0 = nt * 128;
  const int wm = (w >> 1) * 64, wn = (w & 1) * 64;

  f32x4 acc[4][4] = {};

  const int e0 = w * 512 + lane * 8;  // element index of this thread's 16B stage chunk
  const ushort* Abase = Ag + (size_t)m0 * K;
  const ushort* Bbase = Bg + (size_t)n0 * K;

  for (int k0 = 0; k0 < K; k0 += 64) {
#pragma unroll
    for (int q = 0; q < 4; ++q) {
      int e = e0 + q * 2048;
      int row = e >> 6, col = e & 63;
      load_lds16(Abase + (size_t)row * K + (k0 + col), &lA[q * 2048 + w * 512]);
    }
#pragma unroll
    for (int q = 0; q < 4; ++q) {
      int e = e0 + q * 2048;
      int row = e >> 6, col = e & 63;
      load_lds16(Bbase + (size_t)row * K + (k0 + col), &lB[q * 2048 + w * 512]);
    }
    __syncthreads();  // compiler drains vmcnt before barrier (m97 structure)

#pragma unroll
    for (int kk = 0; kk < 2; ++kk) {
      const int ko = kk * 32 + (lane >> 4) * 8;
      bf16x8 af[4], bfr[4];
#pragma unroll
      for (int i = 0; i < 4; ++i)
        af[i] = *(const bf16x8*)&lA[(wm + i * 16 + (lane & 15)) * 64 + ko];
#pragma unroll
      for (int i = 0; i < 4; ++i)
        bfr[i] = *(const bf16x8*)&lB[(wn + i * 16 + (lane & 15)) * 64 + ko];
#pragma unroll
      for (int mi = 0; mi < 4; ++mi)
#pragma unroll
        for (int ni = 0; ni < 4; ++ni)
          acc[mi][ni] = __builtin_amdgcn_mfma_f32_16x16x32_bf16(af[mi], bfr[ni], acc[mi][ni], 0, 0, 0);
    }
    __syncthreads();
  }

  // epilogue: D map (m89-verified): col = lane&15, row = (lane>>4)*4 + e
  const int fr = lane & 15, fq = lane >> 4;
#pragma unroll
  for (int mi = 0; mi < 4; ++mi) {
#pragma unroll
    for (int ni = 0; ni < 4; ++ni) {
#pragma unroll
      for (int e = 0; e < 4; ++e) {
        int row = m0 + wm + mi * 16 + fq * 4 + e;
        int col = colbase + n0 + wn + ni * 16 + fr;
        float v = acc[mi][ni][e];
        if (F32OUT) {
          Cf[(size_t)row * ldc + col] = v;
        } else {
          if (RELU_BF16) v = v > 0.0f ? v : 0.0f;
          Ch[(size_t)row * ldc + col] = f2bf(v);
        }
      }
    }
  }
}

static void run_layer(const ushort* Ain, const float* tbl, ushort* hOut, float* fOut,
                      int K, int N, int Klog2, int a, int b, long c, unsigned mask,
                      int ldc, ushort* wb, size_t avail, hipStream_t stream) {
  long ncmax = (long)(avail / (size_t)((size_t)K * 2));
  ncmax = (ncmax / 128) * 128;
  if (ncmax > N) ncmax = N;
  if (ncmax < 128) ncmax = 128;
  for (int n0 = 0; n0 < N; n0 += (int)ncmax) {
    int nc = (N - n0 < (int)ncmax) ? (N - n0) : (int)ncmax;
    int Cp = (int)((c + (long)n0 * (long)b) & (long)mask);
    int total4 = nc * (K >> 2);
    hipLaunchKernelGGL(mat_wt_kernel, dim3(2048), dim3(256), 0, stream,
                       tbl, wb, Klog2, K - 1, a, b, Cp, mask, total4);
    dim3 g((unsigned)((nc / 128) * 16));
    if (fOut)
      hipLaunchKernelGGL((gemm_bt<false, true>), g, dim3(256), 0, stream,
                         Ain, wb, fOut, (ushort*)nullptr, K, ldc, n0);
    else
      hipLaunchKernelGGL((gemm_bt<true, false>), g, dim3(256), 0, stream,
                         Ain, wb, (float*)nullptr, hOut, K, ldc, n0);
  }
}

extern "C" void kernel_launch(void* const* d_in, const int* in_sizes, int n_in,
                              void* d_out, int out_size, void* d_ws, size_t ws_size,
                              hipStream_t stream) {
  const float* x   = (const float*)d_in[0];
  const float* hw0 = (const float*)d_in[1];
  const float* hw1 = (const float*)d_in[2];
  const float* hw2 = (const float*)d_in[3];
  float* out = (float*)d_out;
  uint8_t* ws = (uint8_t*)d_ws;

  ushort* xb = (ushort*)(ws + 0);                     // 2048x1024 bf16  (4 MB)
  ushort* h1 = (ushort*)(ws + ((size_t)4 << 20));     // 2048x4096 bf16 (16 MB)
  ushort* h2 = (ushort*)(ws + ((size_t)20 << 20));    // 2048x4096 bf16 (16 MB)
  ushort* wb = (ushort*)(ws + ((size_t)36 << 20));    // W^T chunk buffer
  size_t avail = ws_size > ((size_t)36 << 20) ? ws_size - ((size_t)36 << 20)
                                              : (size_t)(128 * 4096 * 2);

  hipLaunchKernelGGL(cvt_bf16_kernel, dim3(1024), dim3(256), 0, stream,
                     (const float4*)x, (ushort4*)xb, 2048 * 1024 / 4);

  // layer 0: [2048,1024] @ [1024,4096], relu -> h1 (bf16)
  run_layer(xb, hw0, h1, nullptr, 1024, 4096, 10, 9973, 31013, 557, 0xFFFFFu, 4096, wb, avail, stream);
  // layer 1: [2048,4096] @ [4096,4096], relu -> h2 (bf16)
  run_layer(h1, hw1, h2, nullptr, 4096, 4096, 12, 10007, 31019, 563, 0xFFFFFu, 4096, wb, avail, stream);
  // layer 2: [2048,4096] @ [4096,32000] -> out (f32)
  run_layer(h2, hw2, nullptr, out, 4096, 32000, 12, 10039, 31039, 569, 0x3FFFFFu, 32000, wb, avail, stream);
}

// Round 2
// 1546.326 us; speedup vs baseline: 1.8276x; 1.8276x over previous
//
#include <hip/hip_runtime.h>
#include <stdint.h>

typedef __attribute__((ext_vector_type(8))) short bf16x8;
typedef __attribute__((ext_vector_type(4))) float f32x4;

__device__ __forceinline__ ushort f2bf(float f) {
  union { float f; uint32_t u; } v; v.f = f;
  return (ushort)((v.u + 0x7FFFu + ((v.u >> 16) & 1u)) >> 16);
}

__device__ __forceinline__ void load_lds16(const void* g, void* l) {
  __builtin_amdgcn_global_load_lds(
      (const __attribute__((address_space(1))) void*)g,
      (__attribute__((address_space(3))) void*)l, 16, 0, 0);
}

// ---- convert x (f32) -> bf16 ----
__global__ void cvt_bf16_kernel(const float4* __restrict__ x, ushort4* __restrict__ o, int n4) {
  int i = blockIdx.x * blockDim.x + threadIdx.x;
  int stride = gridDim.x * blockDim.x;
  for (; i < n4; i += stride) {
    float4 v = x[i];
    o[i] = make_ushort4(f2bf(v.x), f2bf(v.y), f2bf(v.z), f2bf(v.w));
  }
}

// ---- slice-partitioned W^T materialization ----
// For table slice [lo, lo+S): row n's k's with (k*A + n*B + C) mod M in the
// slice form one contiguous run per wrap j (idx = k*A + offs - j*M, stride A).
// One wave per row n; lane = k offset within run (run len <= ceil(S/A) < 64).
// Gathers stay inside the 2MB slice (L2-resident, slices launched serially);
// W^T writes are lane-contiguous (coalesced).
template <int A, int B, int CC, int M, int K, int S>
__global__ __launch_bounds__(256) void mat_slice_kernel(
    const float* __restrict__ t, ushort* __restrict__ wt, int n0, int nc, int lo) {
  const int w = threadIdx.x >> 6, lane = threadIdx.x & 63;
  const int nrel = blockIdx.x * 4 + w;
  if (nrel >= nc) return;
  const int n = n0 + nrel;
  const int offs = (int)(((unsigned)((long)n * B + CC)) & (unsigned)(M - 1));
  constexpr int J = (int)(((long)(K - 1) * A + (M - 1)) / M) + 1;
  constexpr int BIAS = 1024;  // A*BIAS > M for all layers
  ushort* wrow = wt + (size_t)nrel * K;
#pragma unroll 1
  for (int j = 0; j < J; ++j) {
    const int base = j * M + lo - offs;
    int kL = (int)((unsigned)(base + A * BIAS + A - 1) / (unsigned)A) - BIAS;
    int kU = (int)((unsigned)(base + S + A * BIAS + A - 1) / (unsigned)A) - BIAS;
    if (kL < 0) kL = 0;
    if (kU > K) kU = K;
    const int k = kL + lane;
    if (k < kU) {
      const int idx = k * A + offs - j * M;  // in [lo, lo+S)
      wrow[k] = f2bf(t[idx]);
    }
  }
}

// ---- bf16 GEMM: C[M x N-chunk] = A[M x K] @ Bt[N-chunk x K]^T ----
// 128x128 tile, BK=64, 4 waves (2x2), 16x16x32 MFMA, global_load_lds staging.
template <bool RELU_BF16, bool F32OUT>
__global__ __launch_bounds__(256) void gemm_bt(
    const ushort* __restrict__ Ag, const ushort* __restrict__ Bg,
    float* __restrict__ Cf, ushort* __restrict__ Ch,
    int K, int ldc, int colbase) {
  __shared__ ushort lA[128 * 64];
  __shared__ ushort lB[128 * 64];
  const int tid = threadIdx.x;
  const int w = tid >> 6, lane = tid & 63;
  const int mt = blockIdx.x & 15, nt = blockIdx.x >> 4;
  const int m0 = mt * 128, n0 = nt * 128;
  const int wm = (w >> 1) * 64, wn = (w & 1) * 64;

  f32x4 acc[4][4] = {};

  const int e0 = w * 512 + lane * 8;
  const ushort* Abase = Ag + (size_t)m0 * K;
  const ushort* Bbase = Bg + (size_t)n0 * K;

  for (int k0 = 0; k0 < K; k0 += 64) {
#pragma unroll
    for (int q = 0; q < 4; ++q) {
      int e = e0 + q * 2048;
      int row = e >> 6, col = e & 63;
      load_lds16(Abase + (size_t)row * K + (k0 + col), &lA[q * 2048 + w * 512]);
    }
#pragma unroll
    for (int q = 0; q < 4; ++q) {
      int e = e0 + q * 2048;
      int row = e >> 6, col = e & 63;
      load_lds16(Bbase + (size_t)row * K + (k0 + col), &lB[q * 2048 + w * 512]);
    }
    __syncthreads();

#pragma unroll
    for (int kk = 0; kk < 2; ++kk) {
      const int ko = kk * 32 + (lane >> 4) * 8;
      bf16x8 af[4], bfr[4];
#pragma unroll
      for (int i = 0; i < 4; ++i)
        af[i] = *(const bf16x8*)&lA[(wm + i * 16 + (lane & 15)) * 64 + ko];
#pragma unroll
      for (int i = 0; i < 4; ++i)
        bfr[i] = *(const bf16x8*)&lB[(wn + i * 16 + (lane & 15)) * 64 + ko];
#pragma unroll
      for (int mi = 0; mi < 4; ++mi)
#pragma unroll
        for (int ni = 0; ni < 4; ++ni)
          acc[mi][ni] = __builtin_amdgcn_mfma_f32_16x16x32_bf16(af[mi], bfr[ni], acc[mi][ni], 0, 0, 0);
    }
    __syncthreads();
  }

  const int fr = lane & 15, fq = lane >> 4;
#pragma unroll
  for (int mi = 0; mi < 4; ++mi) {
#pragma unroll
    for (int ni = 0; ni < 4; ++ni) {
#pragma unroll
      for (int e = 0; e < 4; ++e) {
        int row = m0 + wm + mi * 16 + fq * 4 + e;
        int col = colbase + n0 + wn + ni * 16 + fr;
        float v = acc[mi][ni][e];
        if (F32OUT) {
          Cf[(size_t)row * ldc + col] = v;
        } else {
          if (RELU_BF16) v = v > 0.0f ? v : 0.0f;
          Ch[(size_t)row * ldc + col] = f2bf(v);
        }
      }
    }
  }
}

template <int A, int B, int CC, int M, int K>
static void run_layer(const ushort* Ain, const float* tbl, ushort* hOut, float* fOut,
                      int N, int ldc, ushort* wb, size_t avail, hipStream_t stream) {
  constexpr int S = 1 << 19;  // 2MB f32 slice: L2-resident per XCD
  long ncmax = (long)(avail / (size_t)((size_t)K * 2));
  ncmax = (ncmax / 128) * 128;
  if (ncmax > N) ncmax = N;
  if (ncmax < 128) ncmax = 128;
  for (int n0 = 0; n0 < N; n0 += (int)ncmax) {
    int nc = (N - n0 < (int)ncmax) ? (N - n0) : (int)ncmax;
    dim3 gm((unsigned)((nc + 3) / 4));
    for (int lo = 0; lo < M; lo += S) {
      hipLaunchKernelGGL((mat_slice_kernel<A, B, CC, M, K, S>), gm, dim3(256), 0, stream,
                         tbl, wb, n0, nc, lo);
    }
    dim3 g((unsigned)((nc / 128) * 16));
    if (fOut)
      hipLaunchKernelGGL((gemm_bt<false, true>), g, dim3(256), 0, stream,
                         Ain, wb, fOut, (ushort*)nullptr, K, ldc, n0);
    else
      hipLaunchKernelGGL((gemm_bt<true, false>), g, dim3(256), 0, stream,
                         Ain, wb, (float*)nullptr, hOut, K, ldc, n0);
  }
}

extern "C" void kernel_launch(void* const* d_in, const int* in_sizes, int n_in,
                              void* d_out, int out_size, void* d_ws, size_t ws_size,
                              hipStream_t stream) {
  const float* x   = (const float*)d_in[0];
  const float* hw0 = (const float*)d_in[1];
  const float* hw1 = (const float*)d_in[2];
  const float* hw2 = (const float*)d_in[3];
  float* out = (float*)d_out;
  uint8_t* ws = (uint8_t*)d_ws;

  ushort* xb = (ushort*)(ws + 0);                     // 2048x1024 bf16  (4 MB)
  ushort* h1 = (ushort*)(ws + ((size_t)4 << 20));     // 2048x4096 bf16 (16 MB)
  ushort* h2 = (ushort*)(ws + ((size_t)20 << 20));    // 2048x4096 bf16 (16 MB)
  ushort* wb = (ushort*)(ws + ((size_t)36 << 20));    // W^T chunk buffer
  size_t avail = ws_size > ((size_t)36 << 20) ? ws_size - ((size_t)36 << 20)
                                              : (size_t)(128 * 4096 * 2);

  hipLaunchKernelGGL(cvt_bf16_kernel, dim3(1024), dim3(256), 0, stream,
                     (const float4*)x, (ushort4*)xb, 2048 * 1024 / 4);

  // layer 0: [2048,1024] @ [1024,4096], relu -> h1 (bf16)
  run_layer<9973, 31013, 557, 1 << 20, 1024>(xb, hw0, h1, nullptr, 4096, 4096, wb, avail, stream);
  // layer 1: [2048,4096] @ [4096,4096], relu -> h2 (bf16)
  run_layer<10007, 31019, 563, 1 << 20, 4096>(h1, hw1, h2, nullptr, 4096, 4096, wb, avail, stream);
  // layer 2: [2048,4096] @ [4096,32000] -> out (f32)
  run_layer<10039, 31039, 569, 1 << 22, 4096>(h2, hw2, nullptr, out, 32000, 32000, wb, avail, stream);
}

// Round 3
// 1233.249 us; speedup vs baseline: 2.2916x; 1.2539x over previous
//
#include <hip/hip_runtime.h>
#include <stdint.h>

typedef __attribute__((ext_vector_type(8))) short bf16x8;
typedef __attribute__((ext_vector_type(4))) float f32x4;

__device__ __forceinline__ ushort f2bf(float f) {
  union { float f; uint32_t u; } v; v.f = f;
  return (ushort)((v.u + 0x7FFFu + ((v.u >> 16) & 1u)) >> 16);
}

__device__ __forceinline__ void load_lds16(const void* g, void* l) {
  __builtin_amdgcn_global_load_lds(
      (const __attribute__((address_space(1))) void*)g,
      (__attribute__((address_space(3))) void*)l, 16, 0, 0);
}

// ---- convert x (f32) -> bf16 ----
__global__ void cvt_bf16_kernel(const float4* __restrict__ x, ushort4* __restrict__ o, int n4) {
  int i = blockIdx.x * blockDim.x + threadIdx.x;
  int stride = gridDim.x * blockDim.x;
  for (; i < n4; i += stride) {
    float4 v = x[i];
    o[i] = make_ushort4(f2bf(v.x), f2bf(v.y), f2bf(v.z), f2bf(v.w));
  }
}

// ---- slice-partitioned W^T materialization (unchanged from R1) ----
template <int A, int B, int CC, int M, int K, int S>
__global__ __launch_bounds__(256) void mat_slice_kernel(
    const float* __restrict__ t, ushort* __restrict__ wt, int n0, int nc, int lo) {
  const int w = threadIdx.x >> 6, lane = threadIdx.x & 63;
  const int nrel = blockIdx.x * 4 + w;
  if (nrel >= nc) return;
  const int n = n0 + nrel;
  const int offs = (int)(((unsigned)((long)n * B + CC)) & (unsigned)(M - 1));
  constexpr int J = (int)(((long)(K - 1) * A + (M - 1)) / M) + 1;
  constexpr int BIAS = 1024;
  ushort* wrow = wt + (size_t)nrel * K;
#pragma unroll 1
  for (int j = 0; j < J; ++j) {
    const int base = j * M + lo - offs;
    int kL = (int)((unsigned)(base + A * BIAS + A - 1) / (unsigned)A) - BIAS;
    int kU = (int)((unsigned)(base + S + A * BIAS + A - 1) / (unsigned)A) - BIAS;
    if (kL < 0) kL = 0;
    if (kU > K) kU = K;
    const int k = kL + lane;
    if (k < kU) {
      const int idx = k * A + offs - j * M;
      wrow[k] = f2bf(t[idx]);
    }
  }
}

// ---- 128x128 2-phase GEMM (kept for layers 0/1) ----
template <bool RELU_BF16, bool F32OUT>
__global__ __launch_bounds__(256) void gemm_bt(
    const ushort* __restrict__ Ag, const ushort* __restrict__ Bg,
    float* __restrict__ Cf, ushort* __restrict__ Ch,
    int K, int ldc, int colbase) {
  __shared__ ushort lA[128 * 64];
  __shared__ ushort lB[128 * 64];
  const int tid = threadIdx.x;
  const int w = tid >> 6, lane = tid & 63;
  const int mt = blockIdx.x & 15, nt = blockIdx.x >> 4;
  const int m0 = mt * 128, n0 = nt * 128;
  const int wm = (w >> 1) * 64, wn = (w & 1) * 64;

  f32x4 acc[4][4] = {};
  const int e0 = w * 512 + lane * 8;
  const ushort* Abase = Ag + (size_t)m0 * K;
  const ushort* Bbase = Bg + (size_t)n0 * K;

  for (int k0 = 0; k0 < K; k0 += 64) {
#pragma unroll
    for (int q = 0; q < 4; ++q) {
      int e = e0 + q * 2048;
      int row = e >> 6, col = e & 63;
      load_lds16(Abase + (size_t)row * K + (k0 + col), &lA[q * 2048 + w * 512]);
    }
#pragma unroll
    for (int q = 0; q < 4; ++q) {
      int e = e0 + q * 2048;
      int row = e >> 6, col = e & 63;
      load_lds16(Bbase + (size_t)row * K + (k0 + col), &lB[q * 2048 + w * 512]);
    }
    __syncthreads();

#pragma unroll
    for (int kk = 0; kk < 2; ++kk) {
      const int ko = kk * 32 + (lane >> 4) * 8;
      bf16x8 af[4], bfr[4];
#pragma unroll
      for (int i = 0; i < 4; ++i)
        af[i] = *(const bf16x8*)&lA[(wm + i * 16 + (lane & 15)) * 64 + ko];
#pragma unroll
      for (int i = 0; i < 4; ++i)
        bfr[i] = *(const bf16x8*)&lB[(wn + i * 16 + (lane & 15)) * 64 + ko];
#pragma unroll
      for (int mi = 0; mi < 4; ++mi)
#pragma unroll
        for (int ni = 0; ni < 4; ++ni)
          acc[mi][ni] = __builtin_amdgcn_mfma_f32_16x16x32_bf16(af[mi], bfr[ni], acc[mi][ni], 0, 0, 0);
    }
    __syncthreads();
  }

  const int fr = lane & 15, fq = lane >> 4;
#pragma unroll
  for (int mi = 0; mi < 4; ++mi)
#pragma unroll
    for (int ni = 0; ni < 4; ++ni)
#pragma unroll
      for (int e = 0; e < 4; ++e) {
        int row = m0 + wm + mi * 16 + fq * 4 + e;
        int col = colbase + n0 + wn + ni * 16 + fr;
        float v = acc[mi][ni][e];
        if (F32OUT) {
          Cf[(size_t)row * ldc + col] = v;
        } else {
          if (RELU_BF16) v = v > 0.0f ? v : 0.0f;
          Ch[(size_t)row * ldc + col] = f2bf(v);
        }
      }
}

// ==== 256x256 8-wave 4-phase counted-vmcnt GEMM (m201-style), f32 out ====
// A[Mx K] @ Bt[N x K]^T. Wave (wr,wc): rows wr*16+mi*32 (mi=0..7), cols wc*64+nj*16.
// LDS linear dest (global_load_lds), XOR-preswizzled global source, swizzled ds_read.
// Per tile t: issue order Bq0,Bq1 | Bq2,Bq3 | Aq0,Aq1 | Aq2,Aq3 (for t+1);
// phase p consumes A-quarter p; steady-state waits vmcnt {4,5,6,3}, never 0.
__device__ __forceinline__ void stq(const ushort* src, size_t qstep, int q,
                                    ushort* dstbase, int tid) {
  load_lds16(src + (size_t)q * qstep, dstbase + q * 4096 + tid * 8);
}

__global__ __launch_bounds__(512, 2) void gemm256(
    const ushort* __restrict__ Ag, const ushort* __restrict__ Bg,
    float* __restrict__ Cf, int K, int ldc, int colbase, int mtiles) {
  __shared__ alignas(16) ushort lds[2 * 2 * 16384];  // 128 KiB: [buf][A,B][256*64]
  const int tid = threadIdx.x;
  const int lane = tid & 63, w = tid >> 6;
  const int wr = w >> 2, wc = w & 3;
  const int fr = lane & 15, fq = lane >> 4, l7 = lane & 7;

  // bijective XCD swizzle (m204)
  const int nwg = (int)gridDim.x, bid = (int)blockIdx.x;
  const int q8 = nwg >> 3, r8 = nwg & 7;
  const int xcd = bid & 7, ix = bid >> 3;
  const int swz = (xcd < r8 ? xcd * (q8 + 1) : r8 * (q8 + 1) + (xcd - r8) * q8) + ix;
  const int m0 = (swz % mtiles) * 256;
  const int n0 = (swz / mtiles) * 256;

  // staging source (pre-swizzled col so LDS stays linear; read applies same XOR)
  const int rowq = tid >> 3;                         // 0..63 within quarter
  const int cswz = ((tid & 7) ^ (rowq & 7)) * 8;     // XOR-swizzled 8-elem unit
  const ushort* sA = Ag + (size_t)(m0 + rowq) * K + cswz;
  const ushort* sB = Bg + (size_t)(n0 + rowq) * K + cswz;
  const size_t qstep = (size_t)64 * (size_t)K;

  // ds_read element offsets (swizzled unit = (kk*4+fq) ^ l7)
  const int au0 = ((0 * 4 + fq) ^ l7) * 8;
  const int au1 = ((1 * 4 + fq) ^ l7) * 8;
  const int abase = (wr * 16 + fr) * 64;
  const int bbase = (wc * 64 + fr) * 64;

  f32x4 acc[8][4] = {};
  bf16x8 aF[2][2], bF[4][2];

  // prologue: stage tile 0 into buf 0 (FIFO: B0,B1,B2,B3,A0,A1,A2,A3)
  {
    ushort* nAv = lds;
    ushort* nBv = lds + 16384;
    stq(sB, qstep, 0, nBv, tid); stq(sB, qstep, 1, nBv, tid);
    stq(sB, qstep, 2, nBv, tid); stq(sB, qstep, 3, nBv, tid);
    stq(sA, qstep, 0, nAv, tid); stq(sA, qstep, 1, nAv, tid);
    stq(sA, qstep, 2, nAv, tid); stq(sA, qstep, 3, nAv, tid);
    sA += 64; sB += 64;
  }
  asm volatile("s_waitcnt vmcnt(3)" ::: "memory");
  __builtin_amdgcn_s_barrier();

#define RDA(P)                                                      \
  aF[0][0] = *(const bf16x8*)(bAv + abase + (2 * (P)) * 2048 + au0); \
  aF[0][1] = *(const bf16x8*)(bAv + abase + (2 * (P)) * 2048 + au1); \
  aF[1][0] = *(const bf16x8*)(bAv + abase + (2 * (P) + 1) * 2048 + au0); \
  aF[1][1] = *(const bf16x8*)(bAv + abase + (2 * (P) + 1) * 2048 + au1);

#define MFMA16(P)                                                   \
  __builtin_amdgcn_s_setprio(1);                                    \
  _Pragma("unroll")                                                 \
  for (int nj = 0; nj < 4; ++nj) {                                  \
    acc[2 * (P)][nj] = __builtin_amdgcn_mfma_f32_16x16x32_bf16(aF[0][0], bF[nj][0], acc[2 * (P)][nj], 0, 0, 0); \
    acc[2 * (P)][nj] = __builtin_amdgcn_mfma_f32_16x16x32_bf16(aF[0][1], bF[nj][1], acc[2 * (P)][nj], 0, 0, 0); \
    acc[2 * (P) + 1][nj] = __builtin_amdgcn_mfma_f32_16x16x32_bf16(aF[1][0], bF[nj][0], acc[2 * (P) + 1][nj], 0, 0, 0); \
    acc[2 * (P) + 1][nj] = __builtin_amdgcn_mfma_f32_16x16x32_bf16(aF[1][1], bF[nj][1], acc[2 * (P) + 1][nj], 0, 0, 0); \
  }                                                                 \
  __builtin_amdgcn_s_setprio(0);

  const int T = K >> 6;
#pragma unroll 1
  for (int t = 0; t < T; ++t) {
    const int b = t & 1;
    ushort* bAv = lds + b * 32768;
    ushort* bBv = bAv + 16384;
    ushort* nAv = lds + (b ^ 1) * 32768;
    ushort* nBv = nAv + 16384;
    const bool pre = (t + 1 < T);

    // phase 0: read A-quarter 0 + all B; stage Bq0,Bq1
    RDA(0);
#pragma unroll
    for (int nj = 0; nj < 4; ++nj) {
      bF[nj][0] = *(const bf16x8*)(bBv + bbase + nj * 1024 + au0);
      bF[nj][1] = *(const bf16x8*)(bBv + bbase + nj * 1024 + au1);
    }
    if (pre) { stq(sB, qstep, 0, nBv, tid); stq(sB, qstep, 1, nBv, tid);
               asm volatile("s_waitcnt vmcnt(4)" ::: "memory"); }
    else     { asm volatile("s_waitcnt vmcnt(2)" ::: "memory"); }
    __builtin_amdgcn_s_barrier();
    MFMA16(0);
    __builtin_amdgcn_s_barrier();

    // phase 1: A-quarter 1; stage Bq2,Bq3
    RDA(1);
    if (pre) { stq(sB, qstep, 2, nBv, tid); stq(sB, qstep, 3, nBv, tid);
               asm volatile("s_waitcnt vmcnt(5)" ::: "memory"); }
    else     { asm volatile("s_waitcnt vmcnt(1)" ::: "memory"); }
    __builtin_amdgcn_s_barrier();
    MFMA16(1);
    __builtin_amdgcn_s_barrier();

    // phase 2: A-quarter 2; stage Aq0,Aq1
    RDA(2);
    if (pre) { stq(sA, qstep, 0, nAv, tid); stq(sA, qstep, 1, nAv, tid);
               asm volatile("s_waitcnt vmcnt(6)" ::: "memory"); }
    else     { asm volatile("s_waitcnt vmcnt(0)" ::: "memory"); }
    __builtin_amdgcn_s_barrier();
    MFMA16(2);
    __builtin_amdgcn_s_barrier();

    // phase 3: A-quarter 3; stage Aq2,Aq3
    RDA(3);
    if (pre) { stq(sA, qstep, 2, nAv, tid); stq(sA, qstep, 3, nAv, tid);
               asm volatile("s_waitcnt vmcnt(3)" ::: "memory"); }
    __builtin_amdgcn_s_barrier();
    MFMA16(3);
    __builtin_amdgcn_s_barrier();

    if (pre) { sA += 64; sB += 64; }
  }
#undef RDA
#undef MFMA16

  // epilogue: C/D map col=lane&15, row=(lane>>4)*4+e (m89)
#pragma unroll
  for (int mi = 0; mi < 8; ++mi)
#pragma unroll
    for (int nj = 0; nj < 4; ++nj)
#pragma unroll
      for (int e = 0; e < 4; ++e) {
        int row = m0 + wr * 16 + mi * 32 + fq * 4 + e;
        int col = colbase + n0 + wc * 64 + nj * 16 + fr;
        Cf[(size_t)row * ldc + col] = acc[mi][nj][e];
      }
}

template <int A, int B, int CC, int M, int K>
static void run_layer(const ushort* Ain, const float* tbl, ushort* hOut, float* fOut,
                      int N, int ldc, ushort* wb, size_t avail, hipStream_t stream) {
  constexpr int S = 1 << 19;
  long ncmax = (long)(avail / (size_t)((size_t)K * 2));
  ncmax = (ncmax / 128) * 128;
  if (ncmax > N) ncmax = N;
  if (ncmax < 128) ncmax = 128;
  for (int n0 = 0; n0 < N; n0 += (int)ncmax) {
    int nc = (N - n0 < (int)ncmax) ? (N - n0) : (int)ncmax;
    dim3 gm((unsigned)((nc + 3) / 4));
    for (int lo = 0; lo < M; lo += S)
      hipLaunchKernelGGL((mat_slice_kernel<A, B, CC, M, K, S>), gm, dim3(256), 0, stream,
                         tbl, wb, n0, nc, lo);
    dim3 g((unsigned)((nc / 128) * 16));
    if (fOut)
      hipLaunchKernelGGL((gemm_bt<false, true>), g, dim3(256), 0, stream,
                         Ain, wb, fOut, (ushort*)nullptr, K, ldc, n0);
    else
      hipLaunchKernelGGL((gemm_bt<true, false>), g, dim3(256), 0, stream,
                         Ain, wb, (float*)nullptr, hOut, K, ldc, n0);
  }
}

extern "C" void kernel_launch(void* const* d_in, const int* in_sizes, int n_in,
                              void* d_out, int out_size, void* d_ws, size_t ws_size,
                              hipStream_t stream) {
  const float* x   = (const float*)d_in[0];
  const float* hw0 = (const float*)d_in[1];
  const float* hw1 = (const float*)d_in[2];
  const float* hw2 = (const float*)d_in[3];
  float* out = (float*)d_out;
  uint8_t* ws = (uint8_t*)d_ws;

  ushort* xb = (ushort*)(ws + 0);                     // 2048x1024 bf16  (4 MB)
  ushort* h1 = (ushort*)(ws + ((size_t)4 << 20));     // 2048x4096 bf16 (16 MB)
  ushort* h2 = (ushort*)(ws + ((size_t)20 << 20));    // 2048x4096 bf16 (16 MB)
  ushort* wb = (ushort*)(ws + ((size_t)36 << 20));    // W^T chunk buffer
  size_t avail = ws_size > ((size_t)36 << 20) ? ws_size - ((size_t)36 << 20)
                                              : (size_t)(128 * 4096 * 2);

  hipLaunchKernelGGL(cvt_bf16_kernel, dim3(1024), dim3(256), 0, stream,
                     (const float4*)x, (ushort4*)xb, 2048 * 1024 / 4);

  // layer 0: [2048,1024] @ [1024,4096], relu -> h1 (bf16)  [128^2 path]
  run_layer<9973, 31013, 557, 1 << 20, 1024>(xb, hw0, h1, nullptr, 4096, 4096, wb, avail, stream);
  // layer 1: [2048,4096] @ [4096,4096], relu -> h2 (bf16)  [128^2 path]
  run_layer<10007, 31019, 563, 1 << 20, 4096>(h1, hw1, h2, nullptr, 4096, 4096, wb, avail, stream);

  // layer 2: [2048,4096] @ [4096,32000] -> out (f32)  [256^2 8-phase path]
  {
    constexpr int K = 4096, N = 32000, S = 1 << 19, M = 1 << 22;
    long ncmax = (long)(avail / (size_t)((size_t)K * 2));
    ncmax = (ncmax / 256) * 256;
    if (ncmax > N) ncmax = N;
    if (ncmax < 256) ncmax = 256;
    for (int n0 = 0; n0 < N; n0 += (int)ncmax) {
      int nc = (N - n0 < (int)ncmax) ? (N - n0) : (int)ncmax;
      dim3 gm((unsigned)((nc + 3) / 4));
      for (int lo = 0; lo < M; lo += S)
        hipLaunchKernelGGL((mat_slice_kernel<10039, 31039, 569, M, K, S>), gm, dim3(256), 0, stream,
                           hw2, wb, n0, nc, lo);
      hipLaunchKernelGGL(gemm256, dim3((unsigned)((nc / 256) * 8)), dim3(512), 0, stream,
                         h2, wb, out, K, N, n0, 8);
    }
  }
}